// Round 4
// baseline (62.755 us; speedup 1.0000x reference)
//
#include <hip/hip_runtime.h>
#include <math.h>

#define N_IMG 64
#define H_IMG 512
#define W_IMG 512
#define EPSF 1e-6f
#define LN2F 0.69314718055994530942f

#define QBLK 16                    // 32-row groups per image (one block each)
#define NBLK (N_IMG * QBLK)        // 1024 main blocks
#define WSSTRIDE 20
// slot: [0]=bce_log2_sum, [1]=fd_diff, [2]=fd_cnt, [3..10]=patch_d[8], [11..18]=patch_cnt[8]

__device__ __forceinline__ float wave_reduce_add(float v) {
#pragma unroll
    for (int off = 32; off > 0; off >>= 1)
        v += __shfl_down(v, off, 64);
    return v;  // valid in lane 0
}

// load one slab's 4 rows (this thread's 4x4 cell) into register buffers
#define LOADS(P_, G_, T) do {                                                   \
    const size_t o_ = (size_t)(T) * 8 * W_IMG;                                  \
    P_[0] = *(const float4*)(pb + o_);                                          \
    P_[1] = *(const float4*)(pb + o_ + W_IMG);                                  \
    P_[2] = *(const float4*)(pb + o_ + 2 * W_IMG);                              \
    P_[3] = *(const float4*)(pb + o_ + 3 * W_IMG);                              \
    G_[0] = *(const float4*)(gb + o_);                                          \
    G_[1] = *(const float4*)(gb + o_ + W_IMG);                                  \
    G_[2] = *(const float4*)(gb + o_ + 2 * W_IMG);                              \
    G_[3] = *(const float4*)(gb + o_ + 3 * W_IMG);                              \
} while (0)

// consume one slab: bce (log2), fd cell, patch partial accumulation
#define PROC(P_, G_) do {                                                       \
    float ssum_ = 0.f, gsum_ = 0.f, pdsum_ = 0.f;                               \
    _Pragma("unroll")                                                           \
    for (int r_ = 0; r_ < 4; ++r_) {                                            \
        const float pv_[4] = {P_[r_].x, P_[r_].y, P_[r_].z, P_[r_].w};          \
        const float gv_[4] = {G_[r_].x, G_[r_].y, G_[r_].z, G_[r_].w};          \
        _Pragma("unroll")                                                       \
        for (int i_ = 0; i_ < 4; ++i_) {                                        \
            const float p_ = pv_[i_], g_ = gv_[i_];                             \
            bce += __log2f(g_ > 0.5f ? p_ : 1.0f - p_);                         \
            const float sig_ = __builtin_amdgcn_rcpf(1.0f + __expf(-p_));       \
            pdsum_ += fabsf(sig_ - g_);                                         \
            gsum_  += g_;                                                       \
            ssum_  += sig_;                                                     \
        }                                                                       \
    }                                                                           \
    const float m0r_ = ssum_ * 0.0625f, m1r_ = gsum_ * 0.0625f;                 \
    const float m0_ = (m0r_ > 0.f && m0r_ < 16.f) ? m0r_ : 0.f;                 \
    const float m1_ = (m1r_ > 0.f && m1r_ < 16.f) ? m1r_ : 0.f;                 \
    fdd += fabsf(m0_ - m1_);                                                    \
    fdc += (m1_ > 0.f) ? 1.f : 0.f;                                             \
    pdacc += pdsum_;                                                            \
    ctacc += gsum_;                                                             \
} while (0)

__global__ __launch_bounds__(256, 4) void loss_main(
    const float* __restrict__ pred, const float* __restrict__ gt,
    float* __restrict__ ws)
{
    __shared__ float l_pd[2][8], l_pc[2][8], l_s[4][3];

    const int b    = blockIdx.x;
    const int n    = b >> 4;           // image
    const int q    = b & 15;           // 32-row group
    const int tid  = threadIdx.x;
    const int w    = tid >> 6;         // wave 0..3
    const int lane = tid & 63;
    const int pr   = tid >> 7;         // 4-row half within each 8-row slab
    const int pcc  = tid & 127;        // 4-col cell index

    const size_t base = ((size_t)(n * H_IMG + q * 32 + pr * 4)) * W_IMG
                      + (size_t)(pcc * 4);
    const float* pb = pred + base;
    const float* gb = gt + base;

    float bce = 0.f, fdd = 0.f, fdc = 0.f, pdacc = 0.f, ctacc = 0.f;

    float4 PA[4], GA[4], PB[4], GB[4];
    // 2-slab-deep register pipeline over the block's 4 slabs
    LOADS(PA, GA, 0);
    LOADS(PB, GB, 1);
    PROC(PA, GA);
    LOADS(PA, GA, 2);
    PROC(PB, GB);
    LOADS(PB, GB, 3);
    PROC(PA, GA);
    PROC(PB, GB);

    // ---- block reduce bce/fdd/fdc ----
    {
        const float b0 = wave_reduce_add(bce);
        const float b1 = wave_reduce_add(fdd);
        const float b2 = wave_reduce_add(fdc);
        if (lane == 0) { l_s[w][0] = b0; l_s[w][1] = b1; l_s[w][2] = b2; }
    }

    // ---- patch partials: 16 consecutive lanes share one 64-col patch column ----
    {
        float d = pdacc, ct = ctacc;
        d += __shfl_down(d, 8, 64);  ct += __shfl_down(ct, 8, 64);
        d += __shfl_down(d, 4, 64);  ct += __shfl_down(ct, 4, 64);
        d += __shfl_down(d, 2, 64);  ct += __shfl_down(ct, 2, 64);
        d += __shfl_down(d, 1, 64);  ct += __shfl_down(ct, 1, 64);
        if ((lane & 15) == 0) {
            const int col = (w & 1) * 4 + (lane >> 4);   // patch col 0..7
            l_pd[pr][col] = d;
            l_pc[pr][col] = ct;
        }
    }
    __syncthreads();

    float* slot = ws + (size_t)b * WSSTRIDE;
    if (tid == 0) {
        slot[0] = l_s[0][0] + l_s[1][0] + l_s[2][0] + l_s[3][0];
        slot[1] = l_s[0][1] + l_s[1][1] + l_s[2][1] + l_s[3][1];
        slot[2] = l_s[0][2] + l_s[1][2] + l_s[2][2] + l_s[3][2];
    }
    if (tid < 8) {
        slot[3  + tid] = l_pd[0][tid] + l_pd[1][tid];
        slot[11 + tid] = l_pc[0][tid] + l_pc[1][tid];
    }
}

__global__ __launch_bounds__(256) void loss_finalize(
    const float* __restrict__ ws, float* __restrict__ out)
{
    __shared__ float l_a[12];
    __shared__ float l_part[256];
    __shared__ float l_cell[64][2];    // 8x8 patch grid: [cell][0]=dsum, [1]=cnt
    const int tid = threadIdx.x;

    // Phase A: bce / fd sums over all 1024 block slots
    float a0 = 0.f, a1 = 0.f, a2 = 0.f;
    for (int b = tid; b < NBLK; b += 256) {
        const float* p = ws + (size_t)b * WSSTRIDE;
        a0 += p[0]; a1 += p[1]; a2 += p[2];
    }
    a0 = wave_reduce_add(a0);
    a1 = wave_reduce_add(a1);
    a2 = wave_reduce_add(a2);
    if ((tid & 63) == 0) {
        const int w = tid >> 6;
        l_a[w * 3 + 0] = a0; l_a[w * 3 + 1] = a1; l_a[w * 3 + 2] = a2;
    }

    // Phase B: 64 cells x {dsum,cnt} x 2 image-halves
    {
        const int cell = tid >> 2, sel = (tid >> 1) & 1, half = tid & 1;
        const int prow = cell >> 3, pcol = cell & 7;
        const int ofs = (sel ? 11 : 3) + pcol;
        float s = 0.f;
        const int n0 = half * 32;
        for (int n = n0; n < n0 + 32; ++n) {
            const int bb = n * QBLK + prow * 2;   // two 32-row blocks per 64-row patch row
            s += ws[(size_t)bb * WSSTRIDE + ofs] + ws[(size_t)(bb + 1) * WSSTRIDE + ofs];
        }
        l_part[tid] = s;
    }
    __syncthreads();
    if (tid < 128) {
        const int cell = tid >> 1, sel = tid & 1;
        l_cell[cell][sel] = l_part[cell * 4 + sel * 2] + l_part[cell * 4 + sel * 2 + 1];
    }
    __syncthreads();

    if (tid != 0) return;

    const float Nf = (float)N_IMG;
    const float bce_sum = (l_a[0] + l_a[3] + l_a[6] + l_a[9]) * LN2F;  // log2 -> ln
    const float fd_d    = l_a[1] + l_a[4] + l_a[7] + l_a[10];
    const float fd_c    = l_a[2] + l_a[5] + l_a[8] + l_a[11];

    const float bce = -bce_sum / (float)((size_t)N_IMG * H_IMG * W_IMG);

    // fd loss
    const float cfd = fd_d / fmaxf(fd_c, EPSF);
    const float vessel = sqrtf(Nf * 512.f * cfd * cfd);
    float st2 = 0.f;
    for (int j = 9; j >= 2; --j) { const float s = exp2f((float)j); st2 += s * s; }
    const float loss_fd = vessel / sqrtf(st2) / Nf;

    // patch loss
    float total = 0.f;
    {   // ps=64: 8x8 grid
        float ts = 0.f;
        for (int i = 0; i < 64; ++i) {
            const float cc = l_cell[i][0] / fmaxf(l_cell[i][1], EPSF);
            ts += 64.f * Nf * cc * cc;
        }
        float local = sqrtf(ts) / 512.f / Nf;
        total += fminf(fmaxf(local, 0.f), 1.f);
    }
    {   // ps=128: 2x2 aggregation
        float ts = 0.f;
        for (int i = 0; i < 4; ++i) for (int j = 0; j < 4; ++j) {
            float d = 0.f, ct = 0.f;
            for (int a = 0; a < 2; ++a) for (int bq = 0; bq < 2; ++bq) {
                const int idx = (2 * i + a) * 8 + (2 * j + bq);
                d += l_cell[idx][0]; ct += l_cell[idx][1];
            }
            const float cc = d / fmaxf(ct, EPSF);
            ts += 128.f * Nf * cc * cc;
        }
        float local = sqrtf(ts) / 512.f / Nf;
        total += fminf(fmaxf(local, 0.f), 1.f);
    }
    {   // ps=256: 4x4 aggregation
        float ts = 0.f;
        for (int i = 0; i < 2; ++i) for (int j = 0; j < 2; ++j) {
            float d = 0.f, ct = 0.f;
            for (int a = 0; a < 4; ++a) for (int bq = 0; bq < 4; ++bq) {
                const int idx = (4 * i + a) * 8 + (4 * j + bq);
                d += l_cell[idx][0]; ct += l_cell[idx][1];
            }
            const float cc = d / fmaxf(ct, EPSF);
            ts += 256.f * Nf * cc * cc;
        }
        float local = sqrtf(ts) / 512.f / Nf;
        total += fminf(fmaxf(local, 0.f), 1.f);
    }
    const float loss_patch = total / 64.f;   // (512/64)^2

    out[0] = 1.1f * bce + 0.02f * loss_fd + 0.03f * loss_patch;
}

extern "C" void kernel_launch(void* const* d_in, const int* in_sizes, int n_in,
                              void* d_out, int out_size, void* d_ws, size_t ws_size,
                              hipStream_t stream)
{
    const float* pred = (const float*)d_in[0];
    const float* gt   = (const float*)d_in[1];
    float* ws  = (float*)d_ws;
    float* out = (float*)d_out;

    // every ws slot is fully written by loss_main each call: no memset needed
    loss_main<<<NBLK, 256, 0, stream>>>(pred, gt, ws);
    loss_finalize<<<1, 256, 0, stream>>>(ws, out);
}

// Round 5
// 44.196 us; speedup vs baseline: 1.4199x; 1.4199x over previous
//
#include <hip/hip_runtime.h>
#include <math.h>

#define N_IMG 64
#define H_IMG 512
#define W_IMG 512
#define EPSF 1e-6f
#define LN2F 0.69314718055994530942f

#define SLAB_ROWS 8
#define SLABS (H_IMG / SLAB_ROWS)      // 64 slabs per image
#define NBLK (N_IMG * SLABS)           // 4096 main blocks
#define WSSTRIDE 20
// slot: [0]=bce_log2_sum, [1]=fd_diff, [2]=fd_cnt, [3..10]=patch_d[8], [11..18]=patch_cnt[8]

__device__ __forceinline__ float wave_reduce_add(float v) {
#pragma unroll
    for (int off = 32; off > 0; off >>= 1)
        v += __shfl_down(v, off, 64);
    return v;  // valid in lane 0
}

__global__ __launch_bounds__(256, 8) void loss_main(
    const float* __restrict__ pred, const float* __restrict__ gt,
    float* __restrict__ ws)
{
    __shared__ float l_pd[2][8], l_pc[2][8], l_s[4][3];

    const int b    = blockIdx.x;
    const int n    = b >> 6;           // image
    const int slab = b & 63;           // 8-row slab
    const int tid  = threadIdx.x;
    const int w    = tid >> 6;         // wave 0..3
    const int lane = tid & 63;
    const int pr   = tid >> 7;         // 4-row half within slab (0..1)
    const int pcc  = tid & 127;        // 4-col cell index

    // thread owns one 4x4 fd pool cell
    const size_t base = ((size_t)(n * H_IMG + slab * SLAB_ROWS + pr * 4)) * W_IMG
                      + (size_t)(pcc * 4);
    const float* pb = pred + base;
    const float* gb = gt + base;

    // ---- hoist ALL loads: 8 dwordx4 in flight, single stall episode ----
    float4 P0 = *(const float4*)(pb);
    float4 P1 = *(const float4*)(pb + W_IMG);
    float4 P2 = *(const float4*)(pb + 2 * W_IMG);
    float4 P3 = *(const float4*)(pb + 3 * W_IMG);
    float4 G0 = *(const float4*)(gb);
    float4 G1 = *(const float4*)(gb + W_IMG);
    float4 G2 = *(const float4*)(gb + 2 * W_IMG);
    float4 G3 = *(const float4*)(gb + 3 * W_IMG);

    float bce = 0.f, pdsum = 0.f, gsum = 0.f, ssum = 0.f;
    {
        const float pv[16] = {P0.x,P0.y,P0.z,P0.w, P1.x,P1.y,P1.z,P1.w,
                              P2.x,P2.y,P2.z,P2.w, P3.x,P3.y,P3.z,P3.w};
        const float gv[16] = {G0.x,G0.y,G0.z,G0.w, G1.x,G1.y,G1.z,G1.w,
                              G2.x,G2.y,G2.z,G2.w, G3.x,G3.y,G3.z,G3.w};
#pragma unroll
        for (int i = 0; i < 16; ++i) {
            const float p = pv[i], g = gv[i];
            // gt exactly 0/1: g*ln(p)+(1-g)*ln(1-p) == ln(g ? p : 1-p); accumulate log2
            bce   += __log2f(g > 0.5f ? p : 1.0f - p);
            const float sig = __builtin_amdgcn_rcpf(1.0f + __expf(-p));
            pdsum += fabsf(sig - g);
            gsum  += g;              // == count(g>0), also fd cell gt-sum
            ssum  += sig;
        }
    }

    // ---- fd loss: this thread's 4x4 cell ----
    const float m0r = ssum * 0.0625f, m1r = gsum * 0.0625f;
    const float m0 = (m0r > 0.f && m0r < 16.f) ? m0r : 0.f;
    const float m1 = (m1r > 0.f && m1r < 16.f) ? m1r : 0.f;
    float fdd = fabsf(m0 - m1);
    float fdc = (m1 > 0.f) ? 1.f : 0.f;

    // ---- block reduce bce/fdd/fdc ----
    {
        const float b0 = wave_reduce_add(bce);
        const float b1 = wave_reduce_add(fdd);
        const float b2 = wave_reduce_add(fdc);
        if (lane == 0) { l_s[w][0] = b0; l_s[w][1] = b1; l_s[w][2] = b2; }
    }

    // ---- patch partials: 16 consecutive lanes share one 64-col patch column ----
    {
        float d = pdsum, ct = gsum;
        d += __shfl_down(d, 8, 64);  ct += __shfl_down(ct, 8, 64);
        d += __shfl_down(d, 4, 64);  ct += __shfl_down(ct, 4, 64);
        d += __shfl_down(d, 2, 64);  ct += __shfl_down(ct, 2, 64);
        d += __shfl_down(d, 1, 64);  ct += __shfl_down(ct, 1, 64);
        if ((lane & 15) == 0) {
            const int col = (w & 1) * 4 + (lane >> 4);   // patch col 0..7
            l_pd[pr][col] = d;
            l_pc[pr][col] = ct;
        }
    }
    __syncthreads();

    float* slot = ws + (size_t)b * WSSTRIDE;
    if (tid == 0) {
        slot[0] = l_s[0][0] + l_s[1][0] + l_s[2][0] + l_s[3][0];
        slot[1] = l_s[0][1] + l_s[1][1] + l_s[2][1] + l_s[3][1];
        slot[2] = l_s[0][2] + l_s[1][2] + l_s[2][2] + l_s[3][2];
    }
    if (tid < 8) {
        slot[3  + tid] = l_pd[0][tid] + l_pd[1][tid];
        slot[11 + tid] = l_pc[0][tid] + l_pc[1][tid];
    }
}

__global__ __launch_bounds__(256) void loss_finalize(
    const float* __restrict__ ws, float* __restrict__ out)
{
    __shared__ float l_a[12];
    __shared__ float l_part[256];
    __shared__ float l_cell[64][2];    // 8x8 patch grid: [cell][0]=dsum, [1]=cnt
    const int tid = threadIdx.x;

    // Phase A: bce / fd sums over all 4096 block slots
    float a0 = 0.f, a1 = 0.f, a2 = 0.f;
    for (int b = tid; b < NBLK; b += 256) {
        const float* p = ws + (size_t)b * WSSTRIDE;
        a0 += p[0]; a1 += p[1]; a2 += p[2];
    }
    a0 = wave_reduce_add(a0);
    a1 = wave_reduce_add(a1);
    a2 = wave_reduce_add(a2);
    if ((tid & 63) == 0) {
        const int w = tid >> 6;
        l_a[w * 3 + 0] = a0; l_a[w * 3 + 1] = a1; l_a[w * 3 + 2] = a2;
    }

    // Phase B: 64 cells x {dsum,cnt} x 2 image-halves
    {
        const int cell = tid >> 2, sel = (tid >> 1) & 1, half = tid & 1;
        const int prow = cell >> 3, pcol = cell & 7;
        const int ofs = (sel ? 11 : 3) + pcol;
        float s = 0.f;
        const int n0 = half * 32;
        for (int n = n0; n < n0 + 32; ++n) {
            const int bb = n * SLABS + prow * 8;   // 8 slabs per 64-row patch row
#pragma unroll
            for (int q = 0; q < 8; ++q)
                s += ws[(size_t)(bb + q) * WSSTRIDE + ofs];
        }
        l_part[tid] = s;
    }
    __syncthreads();
    if (tid < 128) {
        const int cell = tid >> 1, sel = tid & 1;
        l_cell[cell][sel] = l_part[cell * 4 + sel * 2] + l_part[cell * 4 + sel * 2 + 1];
    }
    __syncthreads();

    if (tid != 0) return;

    const float Nf = (float)N_IMG;
    const float bce_sum = (l_a[0] + l_a[3] + l_a[6] + l_a[9]) * LN2F;  // log2 -> ln
    const float fd_d    = l_a[1] + l_a[4] + l_a[7] + l_a[10];
    const float fd_c    = l_a[2] + l_a[5] + l_a[8] + l_a[11];

    const float bce = -bce_sum / (float)((size_t)N_IMG * H_IMG * W_IMG);

    // fd loss
    const float cfd = fd_d / fmaxf(fd_c, EPSF);
    const float vessel = sqrtf(Nf * 512.f * cfd * cfd);
    float st2 = 0.f;
    for (int j = 9; j >= 2; --j) { const float s = exp2f((float)j); st2 += s * s; }
    const float loss_fd = vessel / sqrtf(st2) / Nf;

    // patch loss
    float total = 0.f;
    {   // ps=64: 8x8 grid
        float ts = 0.f;
        for (int i = 0; i < 64; ++i) {
            const float cc = l_cell[i][0] / fmaxf(l_cell[i][1], EPSF);
            ts += 64.f * Nf * cc * cc;
        }
        float local = sqrtf(ts) / 512.f / Nf;
        total += fminf(fmaxf(local, 0.f), 1.f);
    }
    {   // ps=128: 2x2 aggregation
        float ts = 0.f;
        for (int i = 0; i < 4; ++i) for (int j = 0; j < 4; ++j) {
            float d = 0.f, ct = 0.f;
            for (int a = 0; a < 2; ++a) for (int bq = 0; bq < 2; ++bq) {
                const int idx = (2 * i + a) * 8 + (2 * j + bq);
                d += l_cell[idx][0]; ct += l_cell[idx][1];
            }
            const float cc = d / fmaxf(ct, EPSF);
            ts += 128.f * Nf * cc * cc;
        }
        float local = sqrtf(ts) / 512.f / Nf;
        total += fminf(fmaxf(local, 0.f), 1.f);
    }
    {   // ps=256: 4x4 aggregation
        float ts = 0.f;
        for (int i = 0; i < 2; ++i) for (int j = 0; j < 2; ++j) {
            float d = 0.f, ct = 0.f;
            for (int a = 0; a < 4; ++a) for (int bq = 0; bq < 4; ++bq) {
                const int idx = (4 * i + a) * 8 + (4 * j + bq);
                d += l_cell[idx][0]; ct += l_cell[idx][1];
            }
            const float cc = d / fmaxf(ct, EPSF);
            ts += 256.f * Nf * cc * cc;
        }
        float local = sqrtf(ts) / 512.f / Nf;
        total += fminf(fmaxf(local, 0.f), 1.f);
    }
    const float loss_patch = total / 64.f;   // (512/64)^2

    out[0] = 1.1f * bce + 0.02f * loss_fd + 0.03f * loss_patch;
}

extern "C" void kernel_launch(void* const* d_in, const int* in_sizes, int n_in,
                              void* d_out, int out_size, void* d_ws, size_t ws_size,
                              hipStream_t stream)
{
    const float* pred = (const float*)d_in[0];
    const float* gt   = (const float*)d_in[1];
    float* ws  = (float*)d_ws;
    float* out = (float*)d_out;

    // every ws slot is fully written by loss_main each call: no memset needed
    loss_main<<<NBLK, 256, 0, stream>>>(pred, gt, ws);
    loss_finalize<<<1, 256, 0, stream>>>(ws, out);
}

// Round 6
// 38.596 us; speedup vs baseline: 1.6260x; 1.1451x over previous
//
#include <hip/hip_runtime.h>
#include <math.h>

#define N_IMG 64
#define H_IMG 512
#define W_IMG 512
#define EPSF 1e-6f
#define LN2F 0.69314718055994530942f

#define BPI 32                       // blocks per image (16-row stripes)
#define NBLK (N_IMG * BPI)           // 2048 main blocks
#define WSSTRIDE 20
// slot: [0]=bce_log2_sum, [1]=fd_diff, [2]=fd_cnt, [3..10]=patch_d[8], [11..18]=patch_cnt[8]

__device__ __forceinline__ float wave_reduce_add(float v) {
#pragma unroll
    for (int off = 32; off > 0; off >>= 1)
        v += __shfl_down(v, off, 64);
    return v;  // valid in lane 0
}

// consume one float4 pair into bce/pd + per-cell sig/gt sums
#define ACC4(P4, G4, SS, GG) do {                                             \
    const float pv_[4] = {P4.x, P4.y, P4.z, P4.w};                            \
    const float gv_[4] = {G4.x, G4.y, G4.z, G4.w};                            \
    _Pragma("unroll")                                                         \
    for (int i_ = 0; i_ < 4; ++i_) {                                          \
        const float p_ = pv_[i_], g_ = gv_[i_];                               \
        bce += __log2f(g_ > 0.5f ? p_ : 1.0f - p_);                           \
        const float sig_ = __builtin_amdgcn_rcpf(1.0f + __expf(-p_));         \
        pd  += fabsf(sig_ - g_);                                              \
        SS  += sig_;                                                          \
        GG  += g_;                                                            \
    }                                                                         \
} while (0)

__global__ __launch_bounds__(256, 4) void loss_main(
    const float* __restrict__ pred, const float* __restrict__ gt,
    float* __restrict__ ws)
{
    __shared__ float l_pd[4][8], l_pc[4][8], l_s[4][3];

    const int b    = blockIdx.x;
    const int n    = b >> 5;           // image
    const int s    = b & 31;           // 16-row stripe
    const int tid  = threadIdx.x;
    const int w    = tid >> 6;         // wave = 4-row cell-row within stripe
    const int lane = tid & 63;         // 8-col chunk within row

    // thread owns two adjacent 4x4 fd cells: rows s*16+w*4 .. +3, cols lane*8 .. +7
    const size_t base = ((size_t)(n * H_IMG + s * 16 + w * 4)) * W_IMG
                      + (size_t)(lane * 8);
    const float* pb = pred + base;
    const float* gb = gt + base;

    // ---- hoist ALL 16 loads, individually named, pinned before consumption ----
    const float4 PA0 = *(const float4*)(pb);
    const float4 PB0 = *(const float4*)(pb + 4);
    const float4 PA1 = *(const float4*)(pb + W_IMG);
    const float4 PB1 = *(const float4*)(pb + W_IMG + 4);
    const float4 PA2 = *(const float4*)(pb + 2 * W_IMG);
    const float4 PB2 = *(const float4*)(pb + 2 * W_IMG + 4);
    const float4 PA3 = *(const float4*)(pb + 3 * W_IMG);
    const float4 PB3 = *(const float4*)(pb + 3 * W_IMG + 4);
    const float4 GA0 = *(const float4*)(gb);
    const float4 GB0 = *(const float4*)(gb + 4);
    const float4 GA1 = *(const float4*)(gb + W_IMG);
    const float4 GB1 = *(const float4*)(gb + W_IMG + 4);
    const float4 GA2 = *(const float4*)(gb + 2 * W_IMG);
    const float4 GB2 = *(const float4*)(gb + 2 * W_IMG + 4);
    const float4 GA3 = *(const float4*)(gb + 3 * W_IMG);
    const float4 GB3 = *(const float4*)(gb + 3 * W_IMG + 4);
    asm volatile("" ::: "memory");   // pin all loads before any use

    float bce = 0.f, pd = 0.f;
    float ssA = 0.f, ggA = 0.f, ssB = 0.f, ggB = 0.f;
    ACC4(PA0, GA0, ssA, ggA);
    ACC4(PA1, GA1, ssA, ggA);
    ACC4(PA2, GA2, ssA, ggA);
    ACC4(PA3, GA3, ssA, ggA);
    ACC4(PB0, GB0, ssB, ggB);
    ACC4(PB1, GB1, ssB, ggB);
    ACC4(PB2, GB2, ssB, ggB);
    ACC4(PB3, GB3, ssB, ggB);

    // ---- fd loss: this thread's two 4x4 cells ----
    float fdd, fdc;
    {
        const float mA0r = ssA * 0.0625f, mA1r = ggA * 0.0625f;
        const float mB0r = ssB * 0.0625f, mB1r = ggB * 0.0625f;
        const float mA0 = (mA0r > 0.f && mA0r < 16.f) ? mA0r : 0.f;
        const float mA1 = (mA1r > 0.f && mA1r < 16.f) ? mA1r : 0.f;
        const float mB0 = (mB0r > 0.f && mB0r < 16.f) ? mB0r : 0.f;
        const float mB1 = (mB1r > 0.f && mB1r < 16.f) ? mB1r : 0.f;
        fdd = fabsf(mA0 - mA1) + fabsf(mB0 - mB1);
        fdc = ((mA1 > 0.f) ? 1.f : 0.f) + ((mB1 > 0.f) ? 1.f : 0.f);
    }
    const float ct = ggA + ggB;     // patch count contribution

    // ---- block reduce bce/fdd/fdc ----
    {
        const float b0 = wave_reduce_add(bce);
        const float b1 = wave_reduce_add(fdd);
        const float b2 = wave_reduce_add(fdc);
        if (lane == 0) { l_s[w][0] = b0; l_s[w][1] = b1; l_s[w][2] = b2; }
    }

    // ---- patch partials: 8 consecutive lanes share one 64-col patch column ----
    {
        float d = pd, c = ct;
        d += __shfl_down(d, 4, 64);  c += __shfl_down(c, 4, 64);
        d += __shfl_down(d, 2, 64);  c += __shfl_down(c, 2, 64);
        d += __shfl_down(d, 1, 64);  c += __shfl_down(c, 1, 64);
        if ((lane & 7) == 0) {
            l_pd[w][lane >> 3] = d;
            l_pc[w][lane >> 3] = c;
        }
    }
    __syncthreads();

    float* slot = ws + (size_t)b * WSSTRIDE;
    if (tid == 0) {
        slot[0] = l_s[0][0] + l_s[1][0] + l_s[2][0] + l_s[3][0];
        slot[1] = l_s[0][1] + l_s[1][1] + l_s[2][1] + l_s[3][1];
        slot[2] = l_s[0][2] + l_s[1][2] + l_s[2][2] + l_s[3][2];
    }
    if (tid < 8) {
        slot[3  + tid] = l_pd[0][tid] + l_pd[1][tid] + l_pd[2][tid] + l_pd[3][tid];
        slot[11 + tid] = l_pc[0][tid] + l_pc[1][tid] + l_pc[2][tid] + l_pc[3][tid];
    }
}

__global__ __launch_bounds__(256) void loss_finalize(
    const float* __restrict__ ws, float* __restrict__ out)
{
    __shared__ float l_a[12];
    __shared__ float l_part[256];
    __shared__ float l_cell[64][2];    // 8x8 patch grid: [cell][0]=dsum, [1]=cnt
    const int tid = threadIdx.x;

    // Phase A: bce / fd sums over all 2048 block slots
    float a0 = 0.f, a1 = 0.f, a2 = 0.f;
    for (int b = tid; b < NBLK; b += 256) {
        const float* p = ws + (size_t)b * WSSTRIDE;
        a0 += p[0]; a1 += p[1]; a2 += p[2];
    }
    a0 = wave_reduce_add(a0);
    a1 = wave_reduce_add(a1);
    a2 = wave_reduce_add(a2);
    if ((tid & 63) == 0) {
        const int w = tid >> 6;
        l_a[w * 3 + 0] = a0; l_a[w * 3 + 1] = a1; l_a[w * 3 + 2] = a2;
    }

    // Phase B: 64 cells x {dsum,cnt} x 2 image-halves
    {
        const int cell = tid >> 2, sel = (tid >> 1) & 1, half = tid & 1;
        const int prow = cell >> 3, pcol = cell & 7;
        const int ofs = (sel ? 11 : 3) + pcol;
        float s = 0.f;
        const int n0 = half * 32;
        for (int n = n0; n < n0 + 32; ++n) {
            const int bb = n * BPI + prow * 4;   // 4 stripes per 64-row patch row
#pragma unroll
            for (int q = 0; q < 4; ++q)
                s += ws[(size_t)(bb + q) * WSSTRIDE + ofs];
        }
        l_part[tid] = s;
    }
    __syncthreads();
    if (tid < 128) {
        const int cell = tid >> 1, sel = tid & 1;
        l_cell[cell][sel] = l_part[cell * 4 + sel * 2] + l_part[cell * 4 + sel * 2 + 1];
    }
    __syncthreads();

    if (tid != 0) return;

    const float Nf = (float)N_IMG;
    const float bce_sum = (l_a[0] + l_a[3] + l_a[6] + l_a[9]) * LN2F;  // log2 -> ln
    const float fd_d    = l_a[1] + l_a[4] + l_a[7] + l_a[10];
    const float fd_c    = l_a[2] + l_a[5] + l_a[8] + l_a[11];

    const float bce = -bce_sum / (float)((size_t)N_IMG * H_IMG * W_IMG);

    // fd loss
    const float cfd = fd_d / fmaxf(fd_c, EPSF);
    const float vessel = sqrtf(Nf * 512.f * cfd * cfd);
    float st2 = 0.f;
    for (int j = 9; j >= 2; --j) { const float s = exp2f((float)j); st2 += s * s; }
    const float loss_fd = vessel / sqrtf(st2) / Nf;

    // patch loss
    float total = 0.f;
    {   // ps=64: 8x8 grid
        float ts = 0.f;
        for (int i = 0; i < 64; ++i) {
            const float cc = l_cell[i][0] / fmaxf(l_cell[i][1], EPSF);
            ts += 64.f * Nf * cc * cc;
        }
        float local = sqrtf(ts) / 512.f / Nf;
        total += fminf(fmaxf(local, 0.f), 1.f);
    }
    {   // ps=128: 2x2 aggregation
        float ts = 0.f;
        for (int i = 0; i < 4; ++i) for (int j = 0; j < 4; ++j) {
            float d = 0.f, c = 0.f;
            for (int a = 0; a < 2; ++a) for (int bq = 0; bq < 2; ++bq) {
                const int idx = (2 * i + a) * 8 + (2 * j + bq);
                d += l_cell[idx][0]; c += l_cell[idx][1];
            }
            const float cc = d / fmaxf(c, EPSF);
            ts += 128.f * Nf * cc * cc;
        }
        float local = sqrtf(ts) / 512.f / Nf;
        total += fminf(fmaxf(local, 0.f), 1.f);
    }
    {   // ps=256: 4x4 aggregation
        float ts = 0.f;
        for (int i = 0; i < 2; ++i) for (int j = 0; j < 2; ++j) {
            float d = 0.f, c = 0.f;
            for (int a = 0; a < 4; ++a) for (int bq = 0; bq < 4; ++bq) {
                const int idx = (4 * i + a) * 8 + (4 * j + bq);
                d += l_cell[idx][0]; c += l_cell[idx][1];
            }
            const float cc = d / fmaxf(c, EPSF);
            ts += 256.f * Nf * cc * cc;
        }
        float local = sqrtf(ts) / 512.f / Nf;
        total += fminf(fmaxf(local, 0.f), 1.f);
    }
    const float loss_patch = total / 64.f;   // (512/64)^2

    out[0] = 1.1f * bce + 0.02f * loss_fd + 0.03f * loss_patch;
}

extern "C" void kernel_launch(void* const* d_in, const int* in_sizes, int n_in,
                              void* d_out, int out_size, void* d_ws, size_t ws_size,
                              hipStream_t stream)
{
    const float* pred = (const float*)d_in[0];
    const float* gt   = (const float*)d_in[1];
    float* ws  = (float*)d_ws;
    float* out = (float*)d_out;

    // every ws slot is fully written by loss_main each call: no memset needed
    loss_main<<<NBLK, 256, 0, stream>>>(pred, gt, ws);
    loss_finalize<<<1, 256, 0, stream>>>(ws, out);
}

// Round 7
// 34.292 us; speedup vs baseline: 1.8300x; 1.1255x over previous
//
#include <hip/hip_runtime.h>
#include <math.h>

#define N_IMG 64
#define H_IMG 512
#define W_IMG 512
#define EPSF 1e-6f
#define LN2F 0.69314718055994530942f

#define BPI 8                        // blocks per image: 64-row bands (= one patch row)
#define NBLK (N_IMG * BPI)           // 512 blocks
#define WSSTRIDE 20
// slot: [0]=bce_log2_sum, [1]=fd_diff, [2]=fd_cnt, [3..10]=patch_d[8], [11..18]=patch_cnt[8]

__device__ __forceinline__ float wave_reduce_add(float v) {
#pragma unroll
    for (int off = 32; off > 0; off >>= 1)
        v += __shfl_down(v, off, 64);
    return v;  // valid in lane 0
}

__global__ __launch_bounds__(256, 2) void loss_main(
    const float* __restrict__ pred, const float* __restrict__ gt,
    float* __restrict__ ws)
{
    __shared__ float l_pd[4][8], l_pc[4][8], l_s[4][3];

    const int b    = blockIdx.x;
    const int n    = b >> 3;           // image
    const int prow = b & 7;            // 64-row band == patch row
    const int tid  = threadIdx.x;
    const int w    = tid >> 6;         // wave: 16-row sub-band
    const int lane = tid & 63;

    // wave w covers band rows w*16 .. w*16+15; iteration rb covers 4 of them.
    // lane covers cols cb*256 + lane*4 .. +3  (one 4x4 fd cell per (rb,cb) iter)
    const size_t wbase = ((size_t)n * H_IMG + (size_t)prow * 64 + (size_t)w * 16) * W_IMG
                       + (size_t)(lane * 4);

    float bce = 0.f, fdd = 0.f, fdc = 0.f;
    float pd0 = 0.f, ct0 = 0.f, pd1 = 0.f, ct1 = 0.f;

    // one column-half: 4 sequential cell iterations, compiler-pipelined
#define DO_HALF(CB, PDA, CTA)                                                   \
    for (int rb = 0; rb < 4; ++rb) {                                            \
        const float* pb = pred + wbase + (size_t)rb * 4 * W_IMG + (CB) * 256;   \
        const float* gb = gt   + wbase + (size_t)rb * 4 * W_IMG + (CB) * 256;   \
        const float4 P0 = *(const float4*)(pb);                                 \
        const float4 P1 = *(const float4*)(pb + W_IMG);                         \
        const float4 P2 = *(const float4*)(pb + 2 * W_IMG);                     \
        const float4 P3 = *(const float4*)(pb + 3 * W_IMG);                     \
        const float4 G0 = *(const float4*)(gb);                                 \
        const float4 G1 = *(const float4*)(gb + W_IMG);                         \
        const float4 G2 = *(const float4*)(gb + 2 * W_IMG);                     \
        const float4 G3 = *(const float4*)(gb + 3 * W_IMG);                     \
        const float pv[16] = {P0.x,P0.y,P0.z,P0.w, P1.x,P1.y,P1.z,P1.w,         \
                              P2.x,P2.y,P2.z,P2.w, P3.x,P3.y,P3.z,P3.w};        \
        const float gv[16] = {G0.x,G0.y,G0.z,G0.w, G1.x,G1.y,G1.z,G1.w,         \
                              G2.x,G2.y,G2.z,G2.w, G3.x,G3.y,G3.z,G3.w};        \
        float ssum = 0.f, gsum = 0.f, pdsum = 0.f;                              \
        _Pragma("unroll")                                                       \
        for (int i = 0; i < 16; ++i) {                                          \
            const float p = pv[i], g = gv[i];                                   \
            bce += __log2f(g > 0.5f ? p : 1.0f - p);                            \
            const float sig = __builtin_amdgcn_rcpf(1.0f + __expf(-p));         \
            pdsum += fabsf(sig - g);                                            \
            gsum  += g;                                                         \
            ssum  += sig;                                                       \
        }                                                                       \
        const float m0r = ssum * 0.0625f, m1r = gsum * 0.0625f;                 \
        const float m0 = (m0r > 0.f && m0r < 16.f) ? m0r : 0.f;                 \
        const float m1 = (m1r > 0.f && m1r < 16.f) ? m1r : 0.f;                 \
        fdd += fabsf(m0 - m1);                                                  \
        fdc += (m1 > 0.f) ? 1.f : 0.f;                                          \
        PDA += pdsum;                                                           \
        CTA += gsum;                                                            \
    }

    DO_HALF(0, pd0, ct0)
    DO_HALF(1, pd1, ct1)
#undef DO_HALF

    // ---- block reduce bce/fdd/fdc ----
    {
        const float b0 = wave_reduce_add(bce);
        const float b1 = wave_reduce_add(fdd);
        const float b2 = wave_reduce_add(fdc);
        if (lane == 0) { l_s[w][0] = b0; l_s[w][1] = b1; l_s[w][2] = b2; }
    }

    // ---- patch partials: 16-lane groups own one 64-col patch column per half ----
    {
        float d0 = pd0, c0 = ct0, d1 = pd1, c1 = ct1;
        d0 += __shfl_down(d0, 8, 64);  c0 += __shfl_down(c0, 8, 64);
        d0 += __shfl_down(d0, 4, 64);  c0 += __shfl_down(c0, 4, 64);
        d0 += __shfl_down(d0, 2, 64);  c0 += __shfl_down(c0, 2, 64);
        d0 += __shfl_down(d0, 1, 64);  c0 += __shfl_down(c0, 1, 64);
        d1 += __shfl_down(d1, 8, 64);  c1 += __shfl_down(c1, 8, 64);
        d1 += __shfl_down(d1, 4, 64);  c1 += __shfl_down(c1, 4, 64);
        d1 += __shfl_down(d1, 2, 64);  c1 += __shfl_down(c1, 2, 64);
        d1 += __shfl_down(d1, 1, 64);  c1 += __shfl_down(c1, 1, 64);
        if ((lane & 15) == 0) {
            const int g16 = lane >> 4;            // 0..3
            l_pd[w][g16]     = d0;  l_pc[w][g16]     = c0;
            l_pd[w][4 + g16] = d1;  l_pc[w][4 + g16] = c1;
        }
    }
    __syncthreads();

    float* slot = ws + (size_t)b * WSSTRIDE;
    if (tid == 0) {
        slot[0] = l_s[0][0] + l_s[1][0] + l_s[2][0] + l_s[3][0];
        slot[1] = l_s[0][1] + l_s[1][1] + l_s[2][1] + l_s[3][1];
        slot[2] = l_s[0][2] + l_s[1][2] + l_s[2][2] + l_s[3][2];
    }
    if (tid < 8) {
        slot[3  + tid] = l_pd[0][tid] + l_pd[1][tid] + l_pd[2][tid] + l_pd[3][tid];
        slot[11 + tid] = l_pc[0][tid] + l_pc[1][tid] + l_pc[2][tid] + l_pc[3][tid];
    }
}

__global__ __launch_bounds__(256) void loss_finalize(
    const float* __restrict__ ws, float* __restrict__ out)
{
    __shared__ float l_a[12];
    __shared__ float l_cell[64][2];    // 8x8 patch grid: [cell][0]=dsum, [1]=cnt
    const int tid = threadIdx.x;

    // Phase A: bce / fd sums over all 512 block slots
    float a0 = 0.f, a1 = 0.f, a2 = 0.f;
    for (int b = tid; b < NBLK; b += 256) {
        const float* p = ws + (size_t)b * WSSTRIDE;
        a0 += p[0]; a1 += p[1]; a2 += p[2];
    }
    a0 = wave_reduce_add(a0);
    a1 = wave_reduce_add(a1);
    a2 = wave_reduce_add(a2);
    if ((tid & 63) == 0) {
        const int w = tid >> 6;
        l_a[w * 3 + 0] = a0; l_a[w * 3 + 1] = a1; l_a[w * 3 + 2] = a2;
    }

    // Phase B: block b = n*8 + prow holds patch row prow
    if (tid < 128) {
        const int cell = tid >> 1, sel = tid & 1;
        const int prow = cell >> 3, pcol = cell & 7;
        const int ofs = (sel ? 11 : 3) + pcol;
        float s = 0.f;
#pragma unroll 4
        for (int n = 0; n < N_IMG; ++n)
            s += ws[(size_t)(n * BPI + prow) * WSSTRIDE + ofs];
        l_cell[cell][sel] = s;
    }
    __syncthreads();

    if (tid != 0) return;

    const float Nf = (float)N_IMG;
    const float bce_sum = (l_a[0] + l_a[3] + l_a[6] + l_a[9]) * LN2F;  // log2 -> ln
    const float fd_d    = l_a[1] + l_a[4] + l_a[7] + l_a[10];
    const float fd_c    = l_a[2] + l_a[5] + l_a[8] + l_a[11];

    const float bce = -bce_sum / (float)((size_t)N_IMG * H_IMG * W_IMG);

    // fd loss
    const float cfd = fd_d / fmaxf(fd_c, EPSF);
    const float vessel = sqrtf(Nf * 512.f * cfd * cfd);
    float st2 = 0.f;
    for (int j = 9; j >= 2; --j) { const float s = exp2f((float)j); st2 += s * s; }
    const float loss_fd = vessel / sqrtf(st2) / Nf;

    // patch loss
    float total = 0.f;
    {   // ps=64: 8x8 grid
        float ts = 0.f;
        for (int i = 0; i < 64; ++i) {
            const float cc = l_cell[i][0] / fmaxf(l_cell[i][1], EPSF);
            ts += 64.f * Nf * cc * cc;
        }
        float local = sqrtf(ts) / 512.f / Nf;
        total += fminf(fmaxf(local, 0.f), 1.f);
    }
    {   // ps=128: 2x2 aggregation
        float ts = 0.f;
        for (int i = 0; i < 4; ++i) for (int j = 0; j < 4; ++j) {
            float d = 0.f, c = 0.f;
            for (int a = 0; a < 2; ++a) for (int bq = 0; bq < 2; ++bq) {
                const int idx = (2 * i + a) * 8 + (2 * j + bq);
                d += l_cell[idx][0]; c += l_cell[idx][1];
            }
            const float cc = d / fmaxf(c, EPSF);
            ts += 128.f * Nf * cc * cc;
        }
        float local = sqrtf(ts) / 512.f / Nf;
        total += fminf(fmaxf(local, 0.f), 1.f);
    }
    {   // ps=256: 4x4 aggregation
        float ts = 0.f;
        for (int i = 0; i < 2; ++i) for (int j = 0; j < 2; ++j) {
            float d = 0.f, c = 0.f;
            for (int a = 0; a < 4; ++a) for (int bq = 0; bq < 4; ++bq) {
                const int idx = (4 * i + a) * 8 + (4 * j + bq);
                d += l_cell[idx][0]; c += l_cell[idx][1];
            }
            const float cc = d / fmaxf(c, EPSF);
            ts += 256.f * Nf * cc * cc;
        }
        float local = sqrtf(ts) / 512.f / Nf;
        total += fminf(fmaxf(local, 0.f), 1.f);
    }
    const float loss_patch = total / 64.f;   // (512/64)^2

    out[0] = 1.1f * bce + 0.02f * loss_fd + 0.03f * loss_patch;
}

extern "C" void kernel_launch(void* const* d_in, const int* in_sizes, int n_in,
                              void* d_out, int out_size, void* d_ws, size_t ws_size,
                              hipStream_t stream)
{
    const float* pred = (const float*)d_in[0];
    const float* gt   = (const float*)d_in[1];
    float* ws  = (float*)d_ws;
    float* out = (float*)d_out;

    // every ws slot is fully written by loss_main each call: no memset needed
    loss_main<<<NBLK, 256, 0, stream>>>(pred, gt, ws);
    loss_finalize<<<1, 256, 0, stream>>>(ws, out);
}